// Round 13
// baseline (153.085 us; speedup 1.0000x reference)
//
#include <hip/hip_runtime.h>

typedef __attribute__((ext_vector_type(8))) short bf16x8;
typedef __attribute__((ext_vector_type(4))) float f32x4;
typedef __attribute__((ext_vector_type(4))) unsigned short u16x4;
typedef __attribute__((ext_vector_type(2))) unsigned short u16x2;
typedef __attribute__((ext_vector_type(8))) unsigned short u16x8;

#define GLD16(g, l) __builtin_amdgcn_global_load_lds( \
    (const __attribute__((address_space(1))) void*)(g), \
    (__attribute__((address_space(3))) void*)(l), 16, 0, 0)

__device__ __forceinline__ unsigned short f2bf(float f) {
  unsigned u = __float_as_uint(f);
  unsigned r = u + 0x7FFFu + ((u >> 16) & 1u);
  return (unsigned short)(r >> 16);
}
__device__ __forceinline__ float bf2f(unsigned short h) {
  return __uint_as_float(((unsigned)h) << 16);
}

template <int N>
__device__ __forceinline__ void wait_vm() {
  if constexpr (N == 0) asm volatile("s_waitcnt vmcnt(0)" ::: "memory");
  else if constexpr (N == 6) asm volatile("s_waitcnt vmcnt(6)" ::: "memory");
  else static_assert(N == 0, "unsupported vmcnt");
}

// ---------------- prep kernels ----------------

__global__ void k_weff(const float* __restrict__ alpha,
                       const float* __restrict__ dw1,
                       const float* __restrict__ dw3,
                       const float* __restrict__ dw5,
                       float* __restrict__ weff) {
  int tap = blockIdx.x;        // 0..24
  int c = threadIdx.x;         // 0..255
  int dy = tap / 5, dx = tap % 5;
  float v = alpha[3] * dw5[c * 25 + tap];
  if (dy >= 1 && dy <= 3 && dx >= 1 && dx <= 3)
    v += alpha[2] * dw3[c * 9 + (dy - 1) * 3 + (dx - 1)];
  if (tap == 12) v += alpha[1] * dw1[c] + alpha[0];
  weff[tap * 256 + c] = v;
}

// combined weights with INTERLEAVED kv row order (R14-verified harmless, kept).
// Row map: k1[c]->2c, v1[c]->2c+1, k3[c]->512+2c, v3[c]->512+2c+1, Wr[c]->1024+c.
// R28: 4 output rows per block -- thread j loads Bm[m*256+j] ONCE and FMAs into
// 4 accumulators (broadcast arow[m] x4). B re-read traffic 256 MB -> 64 MB of
// L2; same FLOPs, same per-row f32 accumulation order (bitwise-identical).
// Grid 512: bid<256 = Wr copy row; else mat=(bid-256)>>6, i0=((bid-256)&63)*4.
__global__ void k_combine(const float* __restrict__ Wk,
                          const float* __restrict__ Wv,
                          const float* __restrict__ Wr,
                          const float* __restrict__ Wf,
                          const float* __restrict__ Wb,
                          const float* __restrict__ bfv,
                          const float* __restrict__ bbv,
                          short* __restrict__ wcat,
                          float* __restrict__ bias) {
  int j = threadIdx.x;
  int bid = blockIdx.x;
  if (bid < 256) {             // Wr copy
    wcat[(size_t)(1024 + bid) * 256 + j] = (short)f2bf(Wr[bid * 256 + j]);
    if (j == 0) bias[1024 + bid] = 0.f;
    return;
  }
  int q = bid - 256;
  int mat = q >> 6;            // 0:k1 1:k3 2:v1 3:v3
  int i0 = (q & 63) * 4;
  const float* Am = (mat & 1) ? Wb : Wf;
  const float* Bm = (mat < 2) ? Wk : Wv;
  const float* a0 = Am + (size_t)(i0 + 0) * 256;
  const float* a1 = Am + (size_t)(i0 + 1) * 256;
  const float* a2 = Am + (size_t)(i0 + 2) * 256;
  const float* a3 = Am + (size_t)(i0 + 3) * 256;
  float c0 = 0.f, c1 = 0.f, c2 = 0.f, c3 = 0.f;
  for (int m = 0; m < 256; ++m) {
    float bv = Bm[m * 256 + j];
    c0 = fmaf(a0[m], bv, c0);
    c1 = fmaf(a1[m], bv, c1);
    c2 = fmaf(a2[m], bv, c2);
    c3 = fmaf(a3[m], bv, c3);
  }
  float cs[4] = {c0, c1, c2, c3};
#pragma unroll
  for (int r = 0; r < 4; ++r) {
    int i = i0 + r;
    int newrow = ((mat & 1) << 9) + (i << 1) + (mat >> 1);  // interleaved position
    wcat[(size_t)newrow * 256 + j] = (short)f2bf(cs[r]);
    if (j == 0) bias[newrow] = (mat & 1) ? bbv[i] : bfv[i];
  }
}

__global__ void k_wo(const float* __restrict__ Wo, short* __restrict__ wob) {
  int i = blockIdx.x * 256 + threadIdx.x;
  wob[i] = (short)f2bf(Wo[i]);
}

// ---------------- OmniShift: 2-row register sliding-window 5x5 stencil ----------
// R26-verified (150.2 us total): XCD h-stripe swizzle -- xcd=bid&7 owns h-blocks
// [xcd*4, xcd*4+4); within XCD: w fastest (identical rows), hb, then b. Working
// set 384 KB << 4MB L2 -> row re-reads hit own-XCD L2. (256,6): VGPR cap 85.
__global__ __launch_bounds__(256, 6)
void k_shift(const float* __restrict__ x, const float* __restrict__ weff,
             unsigned short* __restrict__ xf) {
  int c = threadIdx.x;
  int xcd = blockIdx.x & 7;
  int j = blockIdx.x >> 3;
  int wb = j & 7;              // w-block (fastest: shares identical rows)
  int hb = (j >> 3) & 3;       // h-block within this XCD's stripe
  int b = j >> 5;              // batch (slowest)
  int w0 = wb * 8;             // 0,8,...,56
  int h0 = (xcd * 4 + hb) * 2; // 0..62

  float wg[5][5];
#pragma unroll
  for (int dy = 0; dy < 5; ++dy)
#pragma unroll
    for (int dx = 0; dx < 5; ++dx)
      wg[dy][dx] = weff[(dy * 5 + dx) * 256 + c];

  const float* xb = x + (size_t)b * 4096 * 256 + c;
  int rowoff[6];
  bool rv[6];
#pragma unroll
  for (int r = 0; r < 6; ++r) {
    int y = h0 + r - 2;
    rv[r] = (y >= 0 && y < 64);
    int yc = y < 0 ? 0 : (y > 63 ? 63 : y);
    rowoff[r] = yc * 64 * 256;
  }

  float win[6][8];
#pragma unroll
  for (int j2 = -2; j2 <= 1; ++j2) {
    int xx = w0 + j2;
    int slot = j2 & 7;                // w0 % 8 == 0 -> static
    bool xv = (xx >= 0);
    int xc = xx < 0 ? 0 : xx;
#pragma unroll
    for (int r = 0; r < 6; ++r) {
      float v = xb[rowoff[r] + xc * 256];
      win[r][slot] = (xv && rv[r]) ? v : 0.f;
    }
  }

  unsigned short* xo = xf + ((size_t)b * 4096 + (size_t)h0 * 64) * 256 + c;
#pragma unroll
  for (int ui = 0; ui < 8; ++ui) {
    int w = w0 + ui;
    {
      int xx = w + 2;
      int slot = (ui + 2) & 7;        // static
      bool xv = (xx < 64);
      int xc = xx > 63 ? 63 : xx;
#pragma unroll
      for (int r = 0; r < 6; ++r) {
        float v = xb[rowoff[r] + xc * 256];
        win[r][slot] = (xv && rv[r]) ? v : 0.f;
      }
    }
#pragma unroll
    for (int j2 = 0; j2 < 2; ++j2) {
      float a0 = 0.f, a1 = 0.f, a2 = 0.f, a3 = 0.f, a4 = 0.f;
#pragma unroll
      for (int dx = 0; dx < 5; ++dx) {
        int slot = (ui - 2 + dx) & 7; // static
        a0 = fmaf(win[j2 + 0][slot], wg[0][dx], a0);
        a1 = fmaf(win[j2 + 1][slot], wg[1][dx], a1);
        a2 = fmaf(win[j2 + 2][slot], wg[2][dx], a2);
        a3 = fmaf(win[j2 + 3][slot], wg[3][dx], a3);
        a4 = fmaf(win[j2 + 4][slot], wg[4][dx], a4);
      }
      xo[((size_t)j2 * 64 + w) * 256] = f2bf(((a0 + a1) + (a2 + a3)) + a4);
    }
  }
}

// ---------------- gemm1: single-buffer bf16 MFMA GEMM ---------------------------
// out[M][N] = A[M][K] * B[N][K]^T. BM x 128 tile, BK=64, 4 waves (2x2), 16x16x32.
// R27-verified (44 us, VGPR 40, Occ 45%): BM=64 -> LDS 24 KB -> 6 blocks/CU at
// (256,6) = 24 waves/CU. The ONLY occupancy raise that doesn't cross the
// register wall (R5/R8/R9: acc must stay <= 64 f32/thread; BM=64 SHRINKS it).
// XOR swizzle on stage-source chunk + ds_read addr (BK=64 regime, 0 conflicts).
// NT>0: XCD A-locality flat grid (R19-verified): xcd=bid&7 owns M/BM/8
// contiguous m-tiles, NT n-tiles temporally adjacent -> A re-reads own-XCD L2.
template <int EPI, int BM, int BK, int NT>
__global__ __launch_bounds__(256, (BM == 64) ? 6 : 4)
void gemm_bt(const short* __restrict__ A, const short* __restrict__ Bm,
             const float* __restrict__ bias,
             void* __restrict__ O0, void* __restrict__ O1,
             int M, int N, int K) {
  constexpr int AE = BM * BK;          // shorts in A buffer
  constexpr int MI = BM / 32;          // m-fragments per wave
  constexpr int CH = BK / 8;           // 16B chunks per row
  constexpr int LA = BM * BK / 2048;   // A gld_lds per thread
  constexpr int LB = BK / 16;          // B gld_lds per thread
  constexpr int RW = 132;              // padded row width for epilogue (f32)
  __shared__ __align__(16) short lds[AE + 128 * BK];

  int t = threadIdx.x;
  int lane = t & 63, wv = t >> 6;
  int wr = wv >> 1, wc = wv & 1;
  int m0, n0;
  if (NT) {
    int x = blockIdx.x & 7;
    int j = blockIdx.x >> 3;
    int mpx = M / (BM * 8);            // m-tiles per XCD
    m0 = (x * mpx + j / NT) * BM;
    n0 = (j % NT) * 128;
  } else {
    m0 = blockIdx.x * BM;
    n0 = blockIdx.y * 128;
  }
  f32x4 acc[MI][4] = {};

  for (int k0 = 0; k0 < K; k0 += BK) {
    // STAGE: linear LDS dest, swizzled global source chunk
#pragma unroll
    for (int i = 0; i < LA; ++i) {
      int cc = t + i * 256;
      int row = cc / CH, kc = cc % CH;
      GLD16(A + (size_t)(m0 + row) * K + k0 + ((kc ^ (row & (CH - 1))) << 3), &lds[cc * 8]);
    }
#pragma unroll
    for (int i = 0; i < LB; ++i) {
      int cc = t + i * 256;
      int row = cc / CH, kc = cc % CH;
      GLD16(Bm + (size_t)(n0 + row) * K + k0 + ((kc ^ (row & (CH - 1))) << 3), &lds[AE + cc * 8]);
    }
    __syncthreads();
    // COMPUTE: same XOR on ds_read address
#pragma unroll
    for (int kk = 0; kk < BK / 32; ++kk) {
      int ch = kk * 4 + (lane >> 4);
      bf16x8 av[MI], bv[4];
#pragma unroll
      for (int i = 0; i < MI; ++i) {
        int row = wr * (BM / 2) + i * 16 + (lane & 15);
        av[i] = *(const bf16x8*)&lds[row * BK + ((ch ^ (row & (CH - 1))) << 3)];
      }
#pragma unroll
      for (int i = 0; i < 4; ++i) {
        int row = wc * 64 + i * 16 + (lane & 15);
        bv[i] = *(const bf16x8*)&lds[AE + row * BK + ((ch ^ (row & (CH - 1))) << 3)];
      }
#pragma unroll
      for (int mi = 0; mi < MI; ++mi)
#pragma unroll
        for (int ni = 0; ni < 4; ++ni)
          acc[mi][ni] = __builtin_amdgcn_mfma_f32_16x16x32_bf16(av[mi], bv[ni], acc[mi][ni], 0, 0, 0);
    }
    __syncthreads();
  }

  // ---- epilogue: LDS transpose (row-major fl) -> coalesced wide stores ----
  float* fl = (float*)lds;   // [32 rows][RW cols] f32 = 16.9 KB
  float bb[4];
  if (EPI == 0) {
#pragma unroll
    for (int ni = 0; ni < 4; ++ni)
      bb[ni] = bias[n0 + wc * 64 + ni * 16 + (lane & 15)];
  }
  int rrow = t >> 3;               // 0..31
  int colb = (t & 7) * 16;
#pragma unroll
  for (int mi = 0; mi < MI; ++mi) {
    if (mi) __syncthreads();       // previous readout done before overwrite
    {
      int r0 = (lane >> 4) * 4;
#pragma unroll
      for (int ni = 0; ni < 4; ++ni) {
        int colL = wc * 64 + (lane & 15) + ni * 16;
        f32x4 v = acc[mi][ni];
#pragma unroll
        for (int j = 0; j < 4; ++j) {
          float vj = v[j];
          if (EPI == 0) vj += bb[ni];
          fl[(wr * 16 + r0 + j) * RW + colL] = vj;
        }
      }
    }
    __syncthreads();
    float vv[16];
#pragma unroll
    for (int q = 0; q < 4; ++q)
      *(f32x4*)&vv[q * 4] = *(const f32x4*)&fl[rrow * RW + colb + q * 4];
    int grow = m0 + (rrow >> 4) * (BM / 2) + mi * 16 + (rrow & 15);
    if (EPI == 0) {
      u16x8 o0, o1;
      if (n0 < 1024) {
#pragma unroll
        for (int q = 0; q < 8; ++q) { o0[q] = f2bf(vv[q]); o1[q] = f2bf(vv[8 + q]); }
        unsigned short* dst = (unsigned short*)O0 + (size_t)grow * 1024 + n0 + colb;
        *(u16x8*)dst = o0;
        *(u16x8*)(dst + 8) = o1;
      } else {
#pragma unroll
        for (int q = 0; q < 8; ++q) {
          o0[q] = f2bf(1.f / (1.f + __expf(-vv[q])));
          o1[q] = f2bf(1.f / (1.f + __expf(-vv[8 + q])));
        }
        unsigned short* dst = (unsigned short*)O1 + (size_t)grow * 256 + (n0 - 1024) + colb;
        *(u16x8*)dst = o0;
        *(u16x8*)(dst + 8) = o1;
      }
    } else {
      float* dst = (float*)O0 + (size_t)grow * N + n0 + colb;
#pragma unroll
      for (int q = 0; q < 4; ++q) {
        f32x4 ov = {vv[q * 4], vv[q * 4 + 1], vv[q * 4 + 2], vv[q * 4 + 3]};
        *(f32x4*)(dst + q * 4) = ov;
      }
    }
  }
}

// ---------------- gemm2: double-buffered deep pipeline (R4 exact) ---------------
// R4-verified ~19 us (~900 TF): BM=64/BK=64, NK=16, depth-2 counted-vmcnt
// pipeline, 3 blocks/CU, natural dim3(M/64, 2) grid (R5: XCD remap hurt here).
// Per iter: wait vmcnt(LD) (current step's loads; next step's stay in flight
// ACROSS the barrier), s_barrier, compute, lgkmcnt(0)+s_barrier, stage k+2.
// NEVER __syncthreads in the K-loop (drains vmcnt(0), kills the pipe).
template <int EPI, int BM, int BK>
__global__ __launch_bounds__(256, 3)
void gemm_db(const short* __restrict__ A, const short* __restrict__ Bm,
             const float* __restrict__ bias,
             void* __restrict__ O0, void* __restrict__ O1,
             int M, int N, int K) {
  constexpr int AE = BM * BK;           // shorts in A region of one buffer
  constexpr int BUFS = (BM + 128) * BK; // shorts per buffer
  constexpr int MI = BM / 32;           // m-fragments per wave
  constexpr int CH = BK / 8;            // 16B chunks per row
  constexpr int LA = BM * BK / 2048;    // A gld_lds per thread per step
  constexpr int LB = BK / 16;           // B gld_lds per thread per step
  constexpr int LD = LA + LB;           // loads in flight per step
  constexpr int RW = 132;               // padded row width for epilogue (f32)
  __shared__ __align__(16) short lds[2 * BUFS];

  int t = threadIdx.x;
  int lane = t & 63, wv = t >> 6;
  int wr = wv >> 1, wc = wv & 1;
  int m0 = blockIdx.x * BM, n0 = blockIdx.y * 128;
  const int NK = K / BK;
  f32x4 acc[MI][4] = {};

  float bb[4];
  if (EPI == 0) {
#pragma unroll
    for (int ni = 0; ni < 4; ++ni)
      bb[ni] = bias[n0 + wc * 64 + ni * 16 + (lane & 15)];
  }

  auto STAGE = [&](int step, int bo) {
    int k0 = step * BK;
#pragma unroll
    for (int i = 0; i < LA; ++i) {
      int cc = t + i * 256;
      int row = cc / CH, kc = cc % CH;
      GLD16(A + (size_t)(m0 + row) * K + k0 + ((kc ^ (row & (CH - 1))) << 3),
            &lds[bo + cc * 8]);
    }
#pragma unroll
    for (int i = 0; i < LB; ++i) {
      int cc = t + i * 256;
      int row = cc / CH, kc = cc % CH;
      GLD16(Bm + (size_t)(n0 + row) * K + k0 + ((kc ^ (row & (CH - 1))) << 3),
            &lds[bo + AE + cc * 8]);
    }
  };
  auto COMPUTE = [&](int bo) {
#pragma unroll
    for (int kk = 0; kk < BK / 32; ++kk) {
      int ch = kk * 4 + (lane >> 4);
      bf16x8 av[MI], bv[4];
#pragma unroll
      for (int i = 0; i < MI; ++i) {
        int row = wr * (BM / 2) + i * 16 + (lane & 15);
        av[i] = *(const bf16x8*)&lds[bo + row * BK + ((ch ^ (row & (CH - 1))) << 3)];
      }
#pragma unroll
      for (int i = 0; i < 4; ++i) {
        int row = wc * 64 + i * 16 + (lane & 15);
        bv[i] = *(const bf16x8*)&lds[bo + AE + row * BK + ((ch ^ (row & (CH - 1))) << 3)];
      }
#pragma unroll
      for (int mi = 0; mi < MI; ++mi)
#pragma unroll
        for (int ni = 0; ni < 4; ++ni)
          acc[mi][ni] = __builtin_amdgcn_mfma_f32_16x16x32_bf16(av[mi], bv[ni], acc[mi][ni], 0, 0, 0);
    }
  };

  STAGE(0, 0);
  STAGE(1, BUFS);
#pragma unroll
  for (int k = 0; k < 16; ++k) {      // bounded by max NK; break inside
    if (k >= NK) break;
    int bo = (k & 1) ? BUFS : 0;
    if (k < NK - 1) wait_vm<LD>();
    else wait_vm<0>();
    __builtin_amdgcn_s_barrier();
    COMPUTE(bo);
    asm volatile("s_waitcnt lgkmcnt(0)" ::: "memory");
    __builtin_amdgcn_s_barrier();
    if (k + 2 < NK) STAGE(k + 2, bo);
  }

  // ---- epilogue: LDS transpose (row-major fl) -> coalesced wide stores ----
  float* fl = (float*)lds;   // [32 rows][RW cols] f32 = 16.9 KB
  int rrow = t >> 3;               // 0..31
  int colb = (t & 7) * 16;
#pragma unroll
  for (int mi = 0; mi < MI; ++mi) {
    if (mi) __syncthreads();       // previous readout done before overwrite
    {
      int r0 = (lane >> 4) * 4;
#pragma unroll
      for (int ni = 0; ni < 4; ++ni) {
        int colL = wc * 64 + (lane & 15) + ni * 16;
        f32x4 v = acc[mi][ni];
#pragma unroll
        for (int j = 0; j < 4; ++j) {
          float vj = v[j];
          if (EPI == 0) vj += bb[ni];
          fl[(wr * 16 + r0 + j) * RW + colL] = vj;
        }
      }
    }
    __syncthreads();
    float vv[16];
#pragma unroll
    for (int q = 0; q < 4; ++q)
      *(f32x4*)&vv[q * 4] = *(const f32x4*)&fl[rrow * RW + colb + q * 4];
    int grow = m0 + (rrow >> 4) * (BM / 2) + mi * 16 + (rrow & 15);
    if (EPI == 0) {
      u16x8 o0, o1;
      if (n0 < 1024) {
#pragma unroll
        for (int q = 0; q < 8; ++q) { o0[q] = f2bf(vv[q]); o1[q] = f2bf(vv[8 + q]); }
        unsigned short* dst = (unsigned short*)O0 + (size_t)grow * 1024 + n0 + colb;
        *(u16x8*)dst = o0;
        *(u16x8*)(dst + 8) = o1;
      } else {
#pragma unroll
        for (int q = 0; q < 8; ++q) {
          o0[q] = f2bf(1.f / (1.f + __expf(-vv[q])));
          o1[q] = f2bf(1.f / (1.f + __expf(-vv[8 + q])));
        }
        unsigned short* dst = (unsigned short*)O1 + (size_t)grow * 256 + (n0 - 1024) + colb;
        *(u16x8*)dst = o0;
        *(u16x8*)(dst + 8) = o1;
      }
    } else {
      float* dst = (float*)O0 + (size_t)grow * N + n0 + colb;
#pragma unroll
      for (int q = 0; q < 4; ++q) {
        f32x4 ov = {vv[q * 4], vv[q * 4 + 1], vv[q * 4 + 2], vv[q * 4 + 3]};
        *(f32x4*)(dst + q * 4) = ov;
      }
    }
  }
}

// ---------------- WKV (software-pipelined; 2 ch/thread, interleaved kv) ---------
// R15-verified prefetch pipeline (4-6 outstanding loads/wave).
// R25-verified: chunk 64 (warmup amp 1.5x -> 1.25x) bought ~6.5 us.
// grid 64 x 2(tr) x 8 = 1024 blocks = 4/CU = 16 waves/CU.
__global__ __launch_bounds__(256, 8)
void k_wkv(const unsigned short* __restrict__ kvb, const unsigned short* __restrict__ srb,
           const float* __restrict__ decay, const float* __restrict__ first,
           unsigned short* __restrict__ xssr) {
  const int T = 4096;
  int tid = threadIdx.x;
  int g = tid >> 7;              // 0: k1/v1 half, 1: k3/v3 half
  int l = tid & 127;
  int c0 = l * 2;
  int tr = blockIdx.y;           // 0 natural, 1 transposed scan order
  int s = (g << 1) | tr;         // stream in concat order k1,k2,k3,k4
  int scol = s * 256;
  int chunk = blockIdx.x;        // 0..63, 64 tokens each
  int b = blockIdx.z;
  const float invT = 1.0f / 4096.0f;

  float P0 = 0.f, P1 = 0.f, Q0 = 0.f, Q1 = 0.f;
  float D0 = __expf(-__expf(decay[scol + c0] * invT));
  float D1 = __expf(-__expf(decay[scol + c0 + 1] * invT));
  float eu0 = __expf(first[scol + c0] * invT);
  float eu1 = __expf(first[scol + c0 + 1] * invT);

  int t0 = chunk * 64;
  int tstart = t0 >= 16 ? t0 - 16 : 0;  // 16-step warmup: weight < e^-16 ~ 1e-7
  int tend = t0 + 64;                   // (tend - tstart) is 64 or 80: even
  const size_t bT = (size_t)b * T;
  const int kvoff = (g << 9) + (c0 << 1);  // [half][c][k|v] in shorts

  auto kvload = [&](int tt) {
    int tok = tr ? (((tt & 63) << 6) | (tt >> 6)) : tt;
    return *(const u16x4*)(kvb + (bT + tok) * 1024 + kvoff);
  };
  auto srload = [&](int tt) {
    return *(const u16x2*)(srb + (bT + tt) * 256 + c0);
  };

  // pipeline prologue: 2 iterations in flight
  u16x4 kvA = kvload(tstart);
  u16x4 kvB = kvload(tstart + 1);
  u16x2 svA = srload(tstart);
  u16x2 svB = srload(tstart + 1);

  for (int tt = tstart; tt < tend; tt += 2) {
    // prefetch tt+2 / tt+3 (clamped: last iter re-reads tend-1, harmless)
    int tp2 = tt + 2 < tend ? tt + 2 : tend - 1;
    int tp3 = tt + 3 < tend ? tt + 3 : tend - 1;
    u16x4 kvC = kvload(tp2);
    u16x4 kvD = kvload(tp3);
    u16x2 svC = srload(tp2);
    u16x2 svD = srload(tp3);

#pragma unroll
    for (int u = 0; u < 2; ++u) {
      int ti = tt + u;
      u16x4 kv4 = u ? kvB : kvA;
      u16x2 sv = u ? svB : svA;
      float k0 = bf2f(kv4[0]), v0 = bf2f(kv4[1]);
      float k1 = bf2f(kv4[2]), v1 = bf2f(kv4[3]);
      float e0 = __expf(k0), e1 = __expf(k1);
      if (ti >= t0) {
        float t0e = e0 * eu0, t1e = e1 * eu1;
        float y0 = fmaf(t0e, v0, P0) * __builtin_amdgcn_rcpf(Q0 + t0e);
        float y1 = fmaf(t1e, v1, P1) * __builtin_amdgcn_rcpf(Q1 + t1e);
        u16x2 ow;
        ow[0] = f2bf(y0 * bf2f(sv[0]));
        ow[1] = f2bf(y1 * bf2f(sv[1]));
        *(u16x2*)(xssr + (bT + ti) * 1024 + scol + c0) = ow;
      }
      P0 = fmaf(P0, D0, e0 * v0);
      Q0 = fmaf(Q0, D0, e0);
      P1 = fmaf(P1, D1, e1 * v1);
      Q1 = fmaf(Q1, D1, e1);
    }
    kvA = kvC; kvB = kvD;
    svA = svC; svB = svD;
  }
}

// ---------------- launch ----------------
extern "C" void kernel_launch(void* const* d_in, const int* in_sizes, int n_in,
                              void* d_out, int out_size, void* d_ws, size_t ws_size,
                              hipStream_t stream) {
  const float* x      = (const float*)d_in[0];
  const float* alpha  = (const float*)d_in[1];
  const float* dw1    = (const float*)d_in[2];
  const float* dw3    = (const float*)d_in[3];
  const float* dw5    = (const float*)d_in[4];
  const float* Wk     = (const float*)d_in[5];
  const float* Wv     = (const float*)d_in[6];
  const float* Wr     = (const float*)d_in[7];
  const float* Wf     = (const float*)d_in[8];
  const float* bfv    = (const float*)d_in[9];
  const float* Wb     = (const float*)d_in[10];
  const float* bbv    = (const float*)d_in[11];
  const float* sdecay = (const float*)d_in[12];
  const float* sfirst = (const float*)d_in[13];
  const float* Wo     = (const float*)d_in[14];
  (void)n_in; (void)out_size; (void)ws_size;

  const int Bn = in_sizes[0] / (4096 * 256);  // 8
  const int MT = Bn * 4096;                    // 32768

  char* ws = (char*)d_ws;
  size_t off = 0;
  auto alloc = [&](size_t bytes) {
    void* p = ws + off;
    off += (bytes + 255) & ~(size_t)255;
    return p;
  };
  short* xf            = (short*)alloc((size_t)MT * 256 * 2);
  unsigned short* kv   = (unsigned short*)alloc((size_t)MT * 1024 * 2);
  unsigned short* srb  = (unsigned short*)alloc((size_t)MT * 256 * 2);
  unsigned short* xssr = (unsigned short*)alloc((size_t)MT * 1024 * 2);
  short* wcat          = (short*)alloc((size_t)1280 * 256 * 2);
  float* bias          = (float*)alloc(1280 * 4);
  float* weff          = (float*)alloc(25 * 256 * 4);
  short* wob           = (short*)alloc((size_t)256 * 1024 * 2);

  k_weff<<<25, 256, 0, stream>>>(alpha, dw1, dw3, dw5, weff);
  // combine: 512 blocks (256 Wr-copy + 4 mats x 64 row-quads), 4 rows/block.
  k_combine<<<512, 256, 0, stream>>>(Wk, Wv, Wr, Wf, Wb, bfv, bbv, wcat, bias);
  k_wo<<<1024, 256, 0, stream>>>(Wo, wob);
  // shift: flat 2048-block grid, XCD h-stripe swizzle (R26-verified).
  k_shift<<<256 * Bn, 256, 0, stream>>>(x, weff, (unsigned short*)xf);
  // gemm1: BM=64 -> 6 blocks/CU (R27-verified, 44 us), XCD A-locality NT=10.
  gemm_bt<0, 64, 64, 10><<<dim3(MT / 64 * 10), 256, 0, stream>>>(
      xf, wcat, bias, kv, srb, MT, 1280, 256);
  // wkv: chunk 64 (R25-verified), 1024 blocks.
  k_wkv<<<dim3(64, 2, Bn), 256, 0, stream>>>(kv, srb, sdecay, sfirst, xssr);
  // gemm2: deep pipe (NK=16), natural grid, 3 blocks/CU (R4 exact).
  gemm_db<1, 64, 64><<<dim3(MT / 64, 2), 256, 0, stream>>>(
      (const short*)xssr, wob, nullptr, d_out, nullptr, MT, 256, 1024);
}

// Round 14
// 145.676 us; speedup vs baseline: 1.0509x; 1.0509x over previous
//
#include <hip/hip_runtime.h>

typedef __attribute__((ext_vector_type(8))) short bf16x8;
typedef __attribute__((ext_vector_type(4))) float f32x4;
typedef __attribute__((ext_vector_type(4))) unsigned short u16x4;
typedef __attribute__((ext_vector_type(2))) unsigned short u16x2;
typedef __attribute__((ext_vector_type(8))) unsigned short u16x8;

#define GLD16(g, l) __builtin_amdgcn_global_load_lds( \
    (const __attribute__((address_space(1))) void*)(g), \
    (__attribute__((address_space(3))) void*)(l), 16, 0, 0)

__device__ __forceinline__ unsigned short f2bf(float f) {
  unsigned u = __float_as_uint(f);
  unsigned r = u + 0x7FFFu + ((u >> 16) & 1u);
  return (unsigned short)(r >> 16);
}
__device__ __forceinline__ float bf2f(unsigned short h) {
  return __uint_as_float(((unsigned)h) << 16);
}

template <int N>
__device__ __forceinline__ void wait_vm() {
  if constexpr (N == 0) asm volatile("s_waitcnt vmcnt(0)" ::: "memory");
  else if constexpr (N == 6) asm volatile("s_waitcnt vmcnt(6)" ::: "memory");
  else static_assert(N == 0, "unsupported vmcnt");
}

// ---------------- fused prep kernel (R29) ---------------------------------------
// One dispatch replaces k_weff (25 blocks) + k_combine (512) + k_wo (1024):
// grid 1561, branch on blockIdx. All three are independent; fusion removes 2
// launch/serialization gaps from the 7-kernel chain. Math bitwise-identical.
// k_combine part is R28's 4-rows-per-block variant (B re-read 256->64 MB L2).
__global__ void k_prep(const float* __restrict__ alpha,
                       const float* __restrict__ dw1,
                       const float* __restrict__ dw3,
                       const float* __restrict__ dw5,
                       float* __restrict__ weff,
                       const float* __restrict__ Wk,
                       const float* __restrict__ Wv,
                       const float* __restrict__ Wr,
                       const float* __restrict__ Wf,
                       const float* __restrict__ Wb,
                       const float* __restrict__ bfv,
                       const float* __restrict__ bbv,
                       short* __restrict__ wcat,
                       float* __restrict__ bias,
                       const float* __restrict__ Wo,
                       short* __restrict__ wob) {
  int bid = blockIdx.x;
  int j = threadIdx.x;
  if (bid < 25) {                       // ---- weff ----
    int tap = bid, c = j;
    int dy = tap / 5, dx = tap % 5;
    float v = alpha[3] * dw5[c * 25 + tap];
    if (dy >= 1 && dy <= 3 && dx >= 1 && dx <= 3)
      v += alpha[2] * dw3[c * 9 + (dy - 1) * 3 + (dx - 1)];
    if (tap == 12) v += alpha[1] * dw1[c] + alpha[0];
    weff[tap * 256 + c] = v;
    return;
  }
  bid -= 25;
  if (bid < 512) {                      // ---- combine (R28: 4 rows/block) ----
    if (bid < 256) {                    // Wr copy
      wcat[(size_t)(1024 + bid) * 256 + j] = (short)f2bf(Wr[bid * 256 + j]);
      if (j == 0) bias[1024 + bid] = 0.f;
      return;
    }
    int q = bid - 256;
    int mat = q >> 6;                   // 0:k1 1:k3 2:v1 3:v3
    int i0 = (q & 63) * 4;
    const float* Am = (mat & 1) ? Wb : Wf;
    const float* Bm = (mat < 2) ? Wk : Wv;
    const float* a0 = Am + (size_t)(i0 + 0) * 256;
    const float* a1 = Am + (size_t)(i0 + 1) * 256;
    const float* a2 = Am + (size_t)(i0 + 2) * 256;
    const float* a3 = Am + (size_t)(i0 + 3) * 256;
    float c0 = 0.f, c1 = 0.f, c2 = 0.f, c3 = 0.f;
    for (int m = 0; m < 256; ++m) {
      float bv = Bm[m * 256 + j];
      c0 = fmaf(a0[m], bv, c0);
      c1 = fmaf(a1[m], bv, c1);
      c2 = fmaf(a2[m], bv, c2);
      c3 = fmaf(a3[m], bv, c3);
    }
    float cs[4] = {c0, c1, c2, c3};
#pragma unroll
    for (int r = 0; r < 4; ++r) {
      int i = i0 + r;
      int newrow = ((mat & 1) << 9) + (i << 1) + (mat >> 1);
      wcat[(size_t)newrow * 256 + j] = (short)f2bf(cs[r]);
      if (j == 0) bias[newrow] = (mat & 1) ? bbv[i] : bfv[i];
    }
    return;
  }
  bid -= 512;                           // ---- wo (1024 blocks) ----
  int i = bid * 256 + j;
  wob[i] = (short)f2bf(Wo[i]);
}

// ---------------- OmniShift: 2-row register sliding-window 5x5 stencil ----------
// R26-verified: XCD h-stripe swizzle -- xcd=bid&7 owns h-blocks [xcd*4,xcd*4+4);
// within XCD: w fastest (identical rows), hb, then b. Working set 384 KB << 4MB
// L2 -> row re-reads hit own-XCD L2. (256,6): VGPR cap 85.
__global__ __launch_bounds__(256, 6)
void k_shift(const float* __restrict__ x, const float* __restrict__ weff,
             unsigned short* __restrict__ xf) {
  int c = threadIdx.x;
  int xcd = blockIdx.x & 7;
  int j = blockIdx.x >> 3;
  int wb = j & 7;              // w-block (fastest: shares identical rows)
  int hb = (j >> 3) & 3;       // h-block within this XCD's stripe
  int b = j >> 5;              // batch (slowest)
  int w0 = wb * 8;             // 0,8,...,56
  int h0 = (xcd * 4 + hb) * 2; // 0..62

  float wg[5][5];
#pragma unroll
  for (int dy = 0; dy < 5; ++dy)
#pragma unroll
    for (int dx = 0; dx < 5; ++dx)
      wg[dy][dx] = weff[(dy * 5 + dx) * 256 + c];

  const float* xb = x + (size_t)b * 4096 * 256 + c;
  int rowoff[6];
  bool rv[6];
#pragma unroll
  for (int r = 0; r < 6; ++r) {
    int y = h0 + r - 2;
    rv[r] = (y >= 0 && y < 64);
    int yc = y < 0 ? 0 : (y > 63 ? 63 : y);
    rowoff[r] = yc * 64 * 256;
  }

  float win[6][8];
#pragma unroll
  for (int j2 = -2; j2 <= 1; ++j2) {
    int xx = w0 + j2;
    int slot = j2 & 7;                // w0 % 8 == 0 -> static
    bool xv = (xx >= 0);
    int xc = xx < 0 ? 0 : xx;
#pragma unroll
    for (int r = 0; r < 6; ++r) {
      float v = xb[rowoff[r] + xc * 256];
      win[r][slot] = (xv && rv[r]) ? v : 0.f;
    }
  }

  unsigned short* xo = xf + ((size_t)b * 4096 + (size_t)h0 * 64) * 256 + c;
#pragma unroll
  for (int ui = 0; ui < 8; ++ui) {
    int w = w0 + ui;
    {
      int xx = w + 2;
      int slot = (ui + 2) & 7;        // static
      bool xv = (xx < 64);
      int xc = xx > 63 ? 63 : xx;
#pragma unroll
      for (int r = 0; r < 6; ++r) {
        float v = xb[rowoff[r] + xc * 256];
        win[r][slot] = (xv && rv[r]) ? v : 0.f;
      }
    }
#pragma unroll
    for (int j2 = 0; j2 < 2; ++j2) {
      float a0 = 0.f, a1 = 0.f, a2 = 0.f, a3 = 0.f, a4 = 0.f;
#pragma unroll
      for (int dx = 0; dx < 5; ++dx) {
        int slot = (ui - 2 + dx) & 7; // static
        a0 = fmaf(win[j2 + 0][slot], wg[0][dx], a0);
        a1 = fmaf(win[j2 + 1][slot], wg[1][dx], a1);
        a2 = fmaf(win[j2 + 2][slot], wg[2][dx], a2);
        a3 = fmaf(win[j2 + 3][slot], wg[3][dx], a3);
        a4 = fmaf(win[j2 + 4][slot], wg[4][dx], a4);
      }
      xo[((size_t)j2 * 64 + w) * 256] = f2bf(((a0 + a1) + (a2 + a3)) + a4);
    }
  }
}

// ---------------- gemm1: single-buffer bf16 MFMA GEMM ---------------------------
// out[M][N] = A[M][K] * B[N][K]^T. BM x 128 tile, BK=64, 4 waves (2x2), 16x16x32.
// R27-verified (44 us, VGPR 40, Occ 48%): BM=64 -> LDS 24 KB -> 6 blocks/CU at
// (256,6) = 24 waves/CU. The ONLY occupancy raise that doesn't cross the
// register wall (R5/R8/R9: acc must stay <= 64 f32/thread; BM=64 SHRINKS it).
// XOR swizzle on stage-source chunk + ds_read addr (BK=64 regime, 0 conflicts).
// NT>0: XCD A-locality flat grid (R19-verified): xcd=bid&7 owns M/BM/8
// contiguous m-tiles, NT n-tiles temporally adjacent -> A re-reads own-XCD L2.
template <int EPI, int BM, int BK, int NT>
__global__ __launch_bounds__(256, (BM == 64) ? 6 : 4)
void gemm_bt(const short* __restrict__ A, const short* __restrict__ Bm,
             const float* __restrict__ bias,
             void* __restrict__ O0, void* __restrict__ O1,
             int M, int N, int K) {
  constexpr int AE = BM * BK;          // shorts in A buffer
  constexpr int MI = BM / 32;          // m-fragments per wave
  constexpr int CH = BK / 8;           // 16B chunks per row
  constexpr int LA = BM * BK / 2048;   // A gld_lds per thread
  constexpr int LB = BK / 16;          // B gld_lds per thread
  constexpr int RW = 132;              // padded row width for epilogue (f32)
  __shared__ __align__(16) short lds[AE + 128 * BK];

  int t = threadIdx.x;
  int lane = t & 63, wv = t >> 6;
  int wr = wv >> 1, wc = wv & 1;
  int m0, n0;
  if (NT) {
    int x = blockIdx.x & 7;
    int j = blockIdx.x >> 3;
    int mpx = M / (BM * 8);            // m-tiles per XCD
    m0 = (x * mpx + j / NT) * BM;
    n0 = (j % NT) * 128;
  } else {
    m0 = blockIdx.x * BM;
    n0 = blockIdx.y * 128;
  }
  f32x4 acc[MI][4] = {};

  for (int k0 = 0; k0 < K; k0 += BK) {
    // STAGE: linear LDS dest, swizzled global source chunk
#pragma unroll
    for (int i = 0; i < LA; ++i) {
      int cc = t + i * 256;
      int row = cc / CH, kc = cc % CH;
      GLD16(A + (size_t)(m0 + row) * K + k0 + ((kc ^ (row & (CH - 1))) << 3), &lds[cc * 8]);
    }
#pragma unroll
    for (int i = 0; i < LB; ++i) {
      int cc = t + i * 256;
      int row = cc / CH, kc = cc % CH;
      GLD16(Bm + (size_t)(n0 + row) * K + k0 + ((kc ^ (row & (CH - 1))) << 3), &lds[AE + cc * 8]);
    }
    __syncthreads();
    // COMPUTE: same XOR on ds_read address
#pragma unroll
    for (int kk = 0; kk < BK / 32; ++kk) {
      int ch = kk * 4 + (lane >> 4);
      bf16x8 av[MI], bv[4];
#pragma unroll
      for (int i = 0; i < MI; ++i) {
        int row = wr * (BM / 2) + i * 16 + (lane & 15);
        av[i] = *(const bf16x8*)&lds[row * BK + ((ch ^ (row & (CH - 1))) << 3)];
      }
#pragma unroll
      for (int i = 0; i < 4; ++i) {
        int row = wc * 64 + i * 16 + (lane & 15);
        bv[i] = *(const bf16x8*)&lds[AE + row * BK + ((ch ^ (row & (CH - 1))) << 3)];
      }
#pragma unroll
      for (int mi = 0; mi < MI; ++mi)
#pragma unroll
        for (int ni = 0; ni < 4; ++ni)
          acc[mi][ni] = __builtin_amdgcn_mfma_f32_16x16x32_bf16(av[mi], bv[ni], acc[mi][ni], 0, 0, 0);
    }
    __syncthreads();
  }

  // ---- epilogue: LDS transpose (row-major fl) -> coalesced wide stores ----
  float* fl = (float*)lds;   // [32 rows][RW cols] f32 = 16.9 KB
  float bb[4];
  if (EPI == 0) {
#pragma unroll
    for (int ni = 0; ni < 4; ++ni)
      bb[ni] = bias[n0 + wc * 64 + ni * 16 + (lane & 15)];
  }
  int rrow = t >> 3;               // 0..31
  int colb = (t & 7) * 16;
#pragma unroll
  for (int mi = 0; mi < MI; ++mi) {
    if (mi) __syncthreads();       // previous readout done before overwrite
    {
      int r0 = (lane >> 4) * 4;
#pragma unroll
      for (int ni = 0; ni < 4; ++ni) {
        int colL = wc * 64 + (lane & 15) + ni * 16;
        f32x4 v = acc[mi][ni];
#pragma unroll
        for (int j = 0; j < 4; ++j) {
          float vj = v[j];
          if (EPI == 0) vj += bb[ni];
          fl[(wr * 16 + r0 + j) * RW + colL] = vj;
        }
      }
    }
    __syncthreads();
    float vv[16];
#pragma unroll
    for (int q = 0; q < 4; ++q)
      *(f32x4*)&vv[q * 4] = *(const f32x4*)&fl[rrow * RW + colb + q * 4];
    int grow = m0 + (rrow >> 4) * (BM / 2) + mi * 16 + (rrow & 15);
    if (EPI == 0) {
      u16x8 o0, o1;
      if (n0 < 1024) {
#pragma unroll
        for (int q = 0; q < 8; ++q) { o0[q] = f2bf(vv[q]); o1[q] = f2bf(vv[8 + q]); }
        unsigned short* dst = (unsigned short*)O0 + (size_t)grow * 1024 + n0 + colb;
        *(u16x8*)dst = o0;
        *(u16x8*)(dst + 8) = o1;
      } else {
#pragma unroll
        for (int q = 0; q < 8; ++q) {
          o0[q] = f2bf(1.f / (1.f + __expf(-vv[q])));
          o1[q] = f2bf(1.f / (1.f + __expf(-vv[8 + q])));
        }
        unsigned short* dst = (unsigned short*)O1 + (size_t)grow * 256 + (n0 - 1024) + colb;
        *(u16x8*)dst = o0;
        *(u16x8*)(dst + 8) = o1;
      }
    } else {
      float* dst = (float*)O0 + (size_t)grow * N + n0 + colb;
#pragma unroll
      for (int q = 0; q < 4; ++q) {
        f32x4 ov = {vv[q * 4], vv[q * 4 + 1], vv[q * 4 + 2], vv[q * 4 + 3]};
        *(f32x4*)(dst + q * 4) = ov;
      }
    }
  }
}

// ---------------- gemm2: double-buffered deep pipeline (R4 exact) ---------------
// R4-verified ~19 us (~900 TF): BM=64/BK=64, NK=16, depth-2 counted-vmcnt
// pipeline, 3 blocks/CU, natural dim3(M/64, 2) grid (R5: XCD remap hurt here).
// Per iter: wait vmcnt(LD) (current step's loads; next step's stay in flight
// ACROSS the barrier), s_barrier, compute, lgkmcnt(0)+s_barrier, stage k+2.
// NEVER __syncthreads in the K-loop (drains vmcnt(0), kills the pipe).
template <int EPI, int BM, int BK>
__global__ __launch_bounds__(256, 3)
void gemm_db(const short* __restrict__ A, const short* __restrict__ Bm,
             const float* __restrict__ bias,
             void* __restrict__ O0, void* __restrict__ O1,
             int M, int N, int K) {
  constexpr int AE = BM * BK;           // shorts in A region of one buffer
  constexpr int BUFS = (BM + 128) * BK; // shorts per buffer
  constexpr int MI = BM / 32;           // m-fragments per wave
  constexpr int CH = BK / 8;            // 16B chunks per row
  constexpr int LA = BM * BK / 2048;    // A gld_lds per thread per step
  constexpr int LB = BK / 16;           // B gld_lds per thread per step
  constexpr int LD = LA + LB;           // loads in flight per step
  constexpr int RW = 132;               // padded row width for epilogue (f32)
  __shared__ __align__(16) short lds[2 * BUFS];

  int t = threadIdx.x;
  int lane = t & 63, wv = t >> 6;
  int wr = wv >> 1, wc = wv & 1;
  int m0 = blockIdx.x * BM, n0 = blockIdx.y * 128;
  const int NK = K / BK;
  f32x4 acc[MI][4] = {};

  float bb[4];
  if (EPI == 0) {
#pragma unroll
    for (int ni = 0; ni < 4; ++ni)
      bb[ni] = bias[n0 + wc * 64 + ni * 16 + (lane & 15)];
  }

  auto STAGE = [&](int step, int bo) {
    int k0 = step * BK;
#pragma unroll
    for (int i = 0; i < LA; ++i) {
      int cc = t + i * 256;
      int row = cc / CH, kc = cc % CH;
      GLD16(A + (size_t)(m0 + row) * K + k0 + ((kc ^ (row & (CH - 1))) << 3),
            &lds[bo + cc * 8]);
    }
#pragma unroll
    for (int i = 0; i < LB; ++i) {
      int cc = t + i * 256;
      int row = cc / CH, kc = cc % CH;
      GLD16(Bm + (size_t)(n0 + row) * K + k0 + ((kc ^ (row & (CH - 1))) << 3),
            &lds[bo + AE + cc * 8]);
    }
  };
  auto COMPUTE = [&](int bo) {
#pragma unroll
    for (int kk = 0; kk < BK / 32; ++kk) {
      int ch = kk * 4 + (lane >> 4);
      bf16x8 av[MI], bv[4];
#pragma unroll
      for (int i = 0; i < MI; ++i) {
        int row = wr * (BM / 2) + i * 16 + (lane & 15);
        av[i] = *(const bf16x8*)&lds[bo + row * BK + ((ch ^ (row & (CH - 1))) << 3)];
      }
#pragma unroll
      for (int i = 0; i < 4; ++i) {
        int row = wc * 64 + i * 16 + (lane & 15);
        bv[i] = *(const bf16x8*)&lds[bo + AE + row * BK + ((ch ^ (row & (CH - 1))) << 3)];
      }
#pragma unroll
      for (int mi = 0; mi < MI; ++mi)
#pragma unroll
        for (int ni = 0; ni < 4; ++ni)
          acc[mi][ni] = __builtin_amdgcn_mfma_f32_16x16x32_bf16(av[mi], bv[ni], acc[mi][ni], 0, 0, 0);
    }
  };

  STAGE(0, 0);
  STAGE(1, BUFS);
#pragma unroll
  for (int k = 0; k < 16; ++k) {      // bounded by max NK; break inside
    if (k >= NK) break;
    int bo = (k & 1) ? BUFS : 0;
    if (k < NK - 1) wait_vm<LD>();
    else wait_vm<0>();
    __builtin_amdgcn_s_barrier();
    COMPUTE(bo);
    asm volatile("s_waitcnt lgkmcnt(0)" ::: "memory");
    __builtin_amdgcn_s_barrier();
    if (k + 2 < NK) STAGE(k + 2, bo);
  }

  // ---- epilogue: LDS transpose (row-major fl) -> coalesced wide stores ----
  float* fl = (float*)lds;   // [32 rows][RW cols] f32 = 16.9 KB
  int rrow = t >> 3;               // 0..31
  int colb = (t & 7) * 16;
#pragma unroll
  for (int mi = 0; mi < MI; ++mi) {
    if (mi) __syncthreads();       // previous readout done before overwrite
    {
      int r0 = (lane >> 4) * 4;
#pragma unroll
      for (int ni = 0; ni < 4; ++ni) {
        int colL = wc * 64 + (lane & 15) + ni * 16;
        f32x4 v = acc[mi][ni];
#pragma unroll
        for (int j = 0; j < 4; ++j) {
          float vj = v[j];
          if (EPI == 0) vj += bb[ni];
          fl[(wr * 16 + r0 + j) * RW + colL] = vj;
        }
      }
    }
    __syncthreads();
    float vv[16];
#pragma unroll
    for (int q = 0; q < 4; ++q)
      *(f32x4*)&vv[q * 4] = *(const f32x4*)&fl[rrow * RW + colb + q * 4];
    int grow = m0 + (rrow >> 4) * (BM / 2) + mi * 16 + (rrow & 15);
    if (EPI == 0) {
      u16x8 o0, o1;
      if (n0 < 1024) {
#pragma unroll
        for (int q = 0; q < 8; ++q) { o0[q] = f2bf(vv[q]); o1[q] = f2bf(vv[8 + q]); }
        unsigned short* dst = (unsigned short*)O0 + (size_t)grow * 1024 + n0 + colb;
        *(u16x8*)dst = o0;
        *(u16x8*)(dst + 8) = o1;
      } else {
#pragma unroll
        for (int q = 0; q < 8; ++q) {
          o0[q] = f2bf(1.f / (1.f + __expf(-vv[q])));
          o1[q] = f2bf(1.f / (1.f + __expf(-vv[8 + q])));
        }
        unsigned short* dst = (unsigned short*)O1 + (size_t)grow * 256 + (n0 - 1024) + colb;
        *(u16x8*)dst = o0;
        *(u16x8*)(dst + 8) = o1;
      }
    } else {
      float* dst = (float*)O0 + (size_t)grow * N + n0 + colb;
#pragma unroll
      for (int q = 0; q < 4; ++q) {
        f32x4 ov = {vv[q * 4], vv[q * 4 + 1], vv[q * 4 + 2], vv[q * 4 + 3]};
        *(f32x4*)(dst + q * 4) = ov;
      }
    }
  }
}

// ---------------- WKV (software-pipelined; 2 ch/thread, interleaved kv) ---------
// R15-verified prefetch pipeline (4-6 outstanding loads/wave).
// R25-verified: chunk 64 (warmup amp 1.5x -> 1.25x) bought ~6.5 us.
// grid 64 x 2(tr) x 8 = 1024 blocks = 4/CU = 16 waves/CU.
__global__ __launch_bounds__(256, 8)
void k_wkv(const unsigned short* __restrict__ kvb, const unsigned short* __restrict__ srb,
           const float* __restrict__ decay, const float* __restrict__ first,
           unsigned short* __restrict__ xssr) {
  const int T = 4096;
  int tid = threadIdx.x;
  int g = tid >> 7;              // 0: k1/v1 half, 1: k3/v3 half
  int l = tid & 127;
  int c0 = l * 2;
  int tr = blockIdx.y;           // 0 natural, 1 transposed scan order
  int s = (g << 1) | tr;         // stream in concat order k1,k2,k3,k4
  int scol = s * 256;
  int chunk = blockIdx.x;        // 0..63, 64 tokens each
  int b = blockIdx.z;
  const float invT = 1.0f / 4096.0f;

  float P0 = 0.f, P1 = 0.f, Q0 = 0.f, Q1 = 0.f;
  float D0 = __expf(-__expf(decay[scol + c0] * invT));
  float D1 = __expf(-__expf(decay[scol + c0 + 1] * invT));
  float eu0 = __expf(first[scol + c0] * invT);
  float eu1 = __expf(first[scol + c0 + 1] * invT);

  int t0 = chunk * 64;
  int tstart = t0 >= 16 ? t0 - 16 : 0;  // 16-step warmup: weight < e^-16 ~ 1e-7
  int tend = t0 + 64;                   // (tend - tstart) is 64 or 80: even
  const size_t bT = (size_t)b * T;
  const int kvoff = (g << 9) + (c0 << 1);  // [half][c][k|v] in shorts

  auto kvload = [&](int tt) {
    int tok = tr ? (((tt & 63) << 6) | (tt >> 6)) : tt;
    return *(const u16x4*)(kvb + (bT + tok) * 1024 + kvoff);
  };
  auto srload = [&](int tt) {
    return *(const u16x2*)(srb + (bT + tt) * 256 + c0);
  };

  // pipeline prologue: 2 iterations in flight
  u16x4 kvA = kvload(tstart);
  u16x4 kvB = kvload(tstart + 1);
  u16x2 svA = srload(tstart);
  u16x2 svB = srload(tstart + 1);

  for (int tt = tstart; tt < tend; tt += 2) {
    // prefetch tt+2 / tt+3 (clamped: last iter re-reads tend-1, harmless)
    int tp2 = tt + 2 < tend ? tt + 2 : tend - 1;
    int tp3 = tt + 3 < tend ? tt + 3 : tend - 1;
    u16x4 kvC = kvload(tp2);
    u16x4 kvD = kvload(tp3);
    u16x2 svC = srload(tp2);
    u16x2 svD = srload(tp3);

#pragma unroll
    for (int u = 0; u < 2; ++u) {
      int ti = tt + u;
      u16x4 kv4 = u ? kvB : kvA;
      u16x2 sv = u ? svB : svA;
      float k0 = bf2f(kv4[0]), v0 = bf2f(kv4[1]);
      float k1 = bf2f(kv4[2]), v1 = bf2f(kv4[3]);
      float e0 = __expf(k0), e1 = __expf(k1);
      if (ti >= t0) {
        float t0e = e0 * eu0, t1e = e1 * eu1;
        float y0 = fmaf(t0e, v0, P0) * __builtin_amdgcn_rcpf(Q0 + t0e);
        float y1 = fmaf(t1e, v1, P1) * __builtin_amdgcn_rcpf(Q1 + t1e);
        u16x2 ow;
        ow[0] = f2bf(y0 * bf2f(sv[0]));
        ow[1] = f2bf(y1 * bf2f(sv[1]));
        *(u16x2*)(xssr + (bT + ti) * 1024 + scol + c0) = ow;
      }
      P0 = fmaf(P0, D0, e0 * v0);
      Q0 = fmaf(Q0, D0, e0);
      P1 = fmaf(P1, D1, e1 * v1);
      Q1 = fmaf(Q1, D1, e1);
    }
    kvA = kvC; kvB = kvD;
    svA = svC; svB = svD;
  }
}

// ---------------- launch ----------------
extern "C" void kernel_launch(void* const* d_in, const int* in_sizes, int n_in,
                              void* d_out, int out_size, void* d_ws, size_t ws_size,
                              hipStream_t stream) {
  const float* x      = (const float*)d_in[0];
  const float* alpha  = (const float*)d_in[1];
  const float* dw1    = (const float*)d_in[2];
  const float* dw3    = (const float*)d_in[3];
  const float* dw5    = (const float*)d_in[4];
  const float* Wk     = (const float*)d_in[5];
  const float* Wv     = (const float*)d_in[6];
  const float* Wr     = (const float*)d_in[7];
  const float* Wf     = (const float*)d_in[8];
  const float* bfv    = (const float*)d_in[9];
  const float* Wb     = (const float*)d_in[10];
  const float* bbv    = (const float*)d_in[11];
  const float* sdecay = (const float*)d_in[12];
  const float* sfirst = (const float*)d_in[13];
  const float* Wo     = (const float*)d_in[14];
  (void)n_in; (void)out_size; (void)ws_size;

  const int Bn = in_sizes[0] / (4096 * 256);  // 8
  const int MT = Bn * 4096;                    // 32768

  char* ws = (char*)d_ws;
  size_t off = 0;
  auto alloc = [&](size_t bytes) {
    void* p = ws + off;
    off += (bytes + 255) & ~(size_t)255;
    return p;
  };
  short* xf            = (short*)alloc((size_t)MT * 256 * 2);
  unsigned short* kv   = (unsigned short*)alloc((size_t)MT * 1024 * 2);
  unsigned short* srb  = (unsigned short*)alloc((size_t)MT * 256 * 2);
  unsigned short* xssr = (unsigned short*)alloc((size_t)MT * 1024 * 2);
  short* wcat          = (short*)alloc((size_t)1280 * 256 * 2);
  float* bias          = (float*)alloc(1280 * 4);
  float* weff          = (float*)alloc(25 * 256 * 4);
  short* wob           = (short*)alloc((size_t)256 * 1024 * 2);

  // fused prep: weff (25) + combine (512) + wo (1024) = 1561 blocks, 1 launch.
  k_prep<<<1561, 256, 0, stream>>>(alpha, dw1, dw3, dw5, weff,
                                   Wk, Wv, Wr, Wf, Wb, bfv, bbv, wcat, bias,
                                   Wo, wob);
  // shift: flat 2048-block grid, XCD h-stripe swizzle (R26-verified).
  k_shift<<<256 * Bn, 256, 0, stream>>>(x, weff, (unsigned short*)xf);
  // gemm1: BM=64 -> 6 blocks/CU (R27-verified, 44 us), XCD A-locality NT=10.
  gemm_bt<0, 64, 64, 10><<<dim3(MT / 64 * 10), 256, 0, stream>>>(
      xf, wcat, bias, kv, srb, MT, 1280, 256);
  // wkv: chunk 64 (R25-verified), 1024 blocks.
  k_wkv<<<dim3(64, 2, Bn), 256, 0, stream>>>(kv, srb, sdecay, sfirst, xssr);
  // gemm2: deep pipe (NK=16), natural grid, 3 blocks/CU (R4 exact).
  gemm_db<1, 64, 64><<<dim3(MT / 64, 2), 256, 0, stream>>>(
      (const short*)xssr, wob, nullptr, d_out, nullptr, MT, 256, 1024);
}

// Round 15
// 141.257 us; speedup vs baseline: 1.0837x; 1.0313x over previous
//
#include <hip/hip_runtime.h>

typedef __attribute__((ext_vector_type(8))) short bf16x8;
typedef __attribute__((ext_vector_type(4))) float f32x4;
typedef __attribute__((ext_vector_type(4))) unsigned short u16x4;
typedef __attribute__((ext_vector_type(2))) unsigned short u16x2;
typedef __attribute__((ext_vector_type(8))) unsigned short u16x8;

#define GLD16(g, l) __builtin_amdgcn_global_load_lds( \
    (const __attribute__((address_space(1))) void*)(g), \
    (__attribute__((address_space(3))) void*)(l), 16, 0, 0)

__device__ __forceinline__ unsigned short f2bf(float f) {
  unsigned u = __float_as_uint(f);
  unsigned r = u + 0x7FFFu + ((u >> 16) & 1u);
  return (unsigned short)(r >> 16);
}
__device__ __forceinline__ float bf2f(unsigned short h) {
  return __uint_as_float(((unsigned)h) << 16);
}

template <int N>
__device__ __forceinline__ void wait_vm() {
  if constexpr (N == 0) asm volatile("s_waitcnt vmcnt(0)" ::: "memory");
  else if constexpr (N == 6) asm volatile("s_waitcnt vmcnt(6)" ::: "memory");
  else static_assert(N == 0, "unsupported vmcnt");
}

// ---------------- fused prep + shift kernel (R30) -------------------------------
// R29 measured launch-boundary cost ~3.5-4 us/gap (7 kernels->5 bought 7.4 us).
// R30 removes one more: shift's only prep dependency was the weff table, which
// each shift thread now computes INLINE from alpha/dw1/dw3/dw5 (same FMA order
// -> bitwise-identical wg; ~35 loads/thread of L2-hot tiny tensors, replacing
// the 25 weff loads). shift + combine + wo are then independent -> ONE dispatch:
// blocks [0,2048) = shift (first: the long pole starts immediately),
// [2048,2560) = combine (R28 4-rows/block), [2560,3584) = wo.
// Shift part: R26-verified XCD h-stripe swizzle (row re-reads own-XCD L2);
// (256,6) bound -> VGPR cap 85 (shift wants ~90 win+wg).
__global__ __launch_bounds__(256, 6)
void k_prep_shift(const float* __restrict__ alpha,
                  const float* __restrict__ dw1,
                  const float* __restrict__ dw3,
                  const float* __restrict__ dw5,
                  const float* __restrict__ x,
                  unsigned short* __restrict__ xf,
                  const float* __restrict__ Wk,
                  const float* __restrict__ Wv,
                  const float* __restrict__ Wr,
                  const float* __restrict__ Wf,
                  const float* __restrict__ Wb,
                  const float* __restrict__ bfv,
                  const float* __restrict__ bbv,
                  short* __restrict__ wcat,
                  float* __restrict__ bias,
                  const float* __restrict__ Wo,
                  short* __restrict__ wob) {
  int bid = blockIdx.x;
  int j = threadIdx.x;

  if (bid >= 2048) {                    // ---- prep tail ----
    bid -= 2048;
    if (bid < 512) {                    // combine (R28: 4 rows/block)
      if (bid < 256) {                  // Wr copy
        wcat[(size_t)(1024 + bid) * 256 + j] = (short)f2bf(Wr[bid * 256 + j]);
        if (j == 0) bias[1024 + bid] = 0.f;
        return;
      }
      int q = bid - 256;
      int mat = q >> 6;                 // 0:k1 1:k3 2:v1 3:v3
      int i0 = (q & 63) * 4;
      const float* Am = (mat & 1) ? Wb : Wf;
      const float* Bm = (mat < 2) ? Wk : Wv;
      const float* a0 = Am + (size_t)(i0 + 0) * 256;
      const float* a1 = Am + (size_t)(i0 + 1) * 256;
      const float* a2 = Am + (size_t)(i0 + 2) * 256;
      const float* a3 = Am + (size_t)(i0 + 3) * 256;
      float c0 = 0.f, c1 = 0.f, c2 = 0.f, c3 = 0.f;
      for (int m = 0; m < 256; ++m) {
        float bv = Bm[m * 256 + j];
        c0 = fmaf(a0[m], bv, c0);
        c1 = fmaf(a1[m], bv, c1);
        c2 = fmaf(a2[m], bv, c2);
        c3 = fmaf(a3[m], bv, c3);
      }
      float cs[4] = {c0, c1, c2, c3};
#pragma unroll
      for (int r = 0; r < 4; ++r) {
        int i = i0 + r;
        int newrow = ((mat & 1) << 9) + (i << 1) + (mat >> 1);
        wcat[(size_t)newrow * 256 + j] = (short)f2bf(cs[r]);
        if (j == 0) bias[newrow] = (mat & 1) ? bbv[i] : bfv[i];
      }
      return;
    }
    bid -= 512;                         // wo (1024 blocks)
    int i = bid * 256 + j;
    wob[i] = (short)f2bf(Wo[i]);
    return;
  }

  // ---- shift (2048 blocks; R26 XCD h-stripe swizzle) ----
  int c = j;
  int xcd = bid & 7;
  int jj = bid >> 3;
  int wb = jj & 7;             // w-block (fastest: shares identical rows)
  int hb = (jj >> 3) & 3;      // h-block within this XCD's stripe
  int b = jj >> 5;             // batch (slowest)
  int w0 = wb * 8;             // 0,8,...,56
  int h0 = (xcd * 4 + hb) * 2; // 0..62

  // inline weff: identical op order to the old k_weff -> bitwise-identical wg.
  float wg[5][5];
#pragma unroll
  for (int tap = 0; tap < 25; ++tap) {
    int dy = tap / 5, dx = tap % 5;
    float v = alpha[3] * dw5[c * 25 + tap];
    if (dy >= 1 && dy <= 3 && dx >= 1 && dx <= 3)
      v += alpha[2] * dw3[c * 9 + (dy - 1) * 3 + (dx - 1)];
    if (tap == 12) v += alpha[1] * dw1[c] + alpha[0];
    wg[dy][dx] = v;
  }

  const float* xb = x + (size_t)b * 4096 * 256 + c;
  int rowoff[6];
  bool rv[6];
#pragma unroll
  for (int r = 0; r < 6; ++r) {
    int y = h0 + r - 2;
    rv[r] = (y >= 0 && y < 64);
    int yc = y < 0 ? 0 : (y > 63 ? 63 : y);
    rowoff[r] = yc * 64 * 256;
  }

  float win[6][8];
#pragma unroll
  for (int j2 = -2; j2 <= 1; ++j2) {
    int xx = w0 + j2;
    int slot = j2 & 7;                // w0 % 8 == 0 -> static
    bool xv = (xx >= 0);
    int xc = xx < 0 ? 0 : xx;
#pragma unroll
    for (int r = 0; r < 6; ++r) {
      float v = xb[rowoff[r] + xc * 256];
      win[r][slot] = (xv && rv[r]) ? v : 0.f;
    }
  }

  unsigned short* xo = xf + ((size_t)b * 4096 + (size_t)h0 * 64) * 256 + c;
#pragma unroll
  for (int ui = 0; ui < 8; ++ui) {
    int w = w0 + ui;
    {
      int xx = w + 2;
      int slot = (ui + 2) & 7;        // static
      bool xv = (xx < 64);
      int xc = xx > 63 ? 63 : xx;
#pragma unroll
      for (int r = 0; r < 6; ++r) {
        float v = xb[rowoff[r] + xc * 256];
        win[r][slot] = (xv && rv[r]) ? v : 0.f;
      }
    }
#pragma unroll
    for (int j2 = 0; j2 < 2; ++j2) {
      float a0 = 0.f, a1 = 0.f, a2 = 0.f, a3 = 0.f, a4 = 0.f;
#pragma unroll
      for (int dx = 0; dx < 5; ++dx) {
        int slot = (ui - 2 + dx) & 7; // static
        a0 = fmaf(win[j2 + 0][slot], wg[0][dx], a0);
        a1 = fmaf(win[j2 + 1][slot], wg[1][dx], a1);
        a2 = fmaf(win[j2 + 2][slot], wg[2][dx], a2);
        a3 = fmaf(win[j2 + 3][slot], wg[3][dx], a3);
        a4 = fmaf(win[j2 + 4][slot], wg[4][dx], a4);
      }
      xo[((size_t)j2 * 64 + w) * 256] = f2bf(((a0 + a1) + (a2 + a3)) + a4);
    }
  }
}

// ---------------- gemm1: single-buffer bf16 MFMA GEMM ---------------------------
// out[M][N] = A[M][K] * B[N][K]^T. BM x 128 tile, BK=64, 4 waves (2x2), 16x16x32.
// R27-verified (44 us, VGPR 40, Occ 48%): BM=64 -> LDS 24 KB -> 6 blocks/CU at
// (256,6) = 24 waves/CU. The ONLY occupancy raise that doesn't cross the
// register wall (R5/R8/R9: acc must stay <= 64 f32/thread; BM=64 SHRINKS it).
// XOR swizzle on stage-source chunk + ds_read addr (BK=64 regime, 0 conflicts).
// NT>0: XCD A-locality flat grid (R19-verified): xcd=bid&7 owns M/BM/8
// contiguous m-tiles, NT n-tiles temporally adjacent -> A re-reads own-XCD L2.
template <int EPI, int BM, int BK, int NT>
__global__ __launch_bounds__(256, (BM == 64) ? 6 : 4)
void gemm_bt(const short* __restrict__ A, const short* __restrict__ Bm,
             const float* __restrict__ bias,
             void* __restrict__ O0, void* __restrict__ O1,
             int M, int N, int K) {
  constexpr int AE = BM * BK;          // shorts in A buffer
  constexpr int MI = BM / 32;          // m-fragments per wave
  constexpr int CH = BK / 8;           // 16B chunks per row
  constexpr int LA = BM * BK / 2048;   // A gld_lds per thread
  constexpr int LB = BK / 16;          // B gld_lds per thread
  constexpr int RW = 132;              // padded row width for epilogue (f32)
  __shared__ __align__(16) short lds[AE + 128 * BK];

  int t = threadIdx.x;
  int lane = t & 63, wv = t >> 6;
  int wr = wv >> 1, wc = wv & 1;
  int m0, n0;
  if (NT) {
    int x = blockIdx.x & 7;
    int j = blockIdx.x >> 3;
    int mpx = M / (BM * 8);            // m-tiles per XCD
    m0 = (x * mpx + j / NT) * BM;
    n0 = (j % NT) * 128;
  } else {
    m0 = blockIdx.x * BM;
    n0 = blockIdx.y * 128;
  }
  f32x4 acc[MI][4] = {};

  for (int k0 = 0; k0 < K; k0 += BK) {
    // STAGE: linear LDS dest, swizzled global source chunk
#pragma unroll
    for (int i = 0; i < LA; ++i) {
      int cc = t + i * 256;
      int row = cc / CH, kc = cc % CH;
      GLD16(A + (size_t)(m0 + row) * K + k0 + ((kc ^ (row & (CH - 1))) << 3), &lds[cc * 8]);
    }
#pragma unroll
    for (int i = 0; i < LB; ++i) {
      int cc = t + i * 256;
      int row = cc / CH, kc = cc % CH;
      GLD16(Bm + (size_t)(n0 + row) * K + k0 + ((kc ^ (row & (CH - 1))) << 3), &lds[AE + cc * 8]);
    }
    __syncthreads();
    // COMPUTE: same XOR on ds_read address
#pragma unroll
    for (int kk = 0; kk < BK / 32; ++kk) {
      int ch = kk * 4 + (lane >> 4);
      bf16x8 av[MI], bv[4];
#pragma unroll
      for (int i = 0; i < MI; ++i) {
        int row = wr * (BM / 2) + i * 16 + (lane & 15);
        av[i] = *(const bf16x8*)&lds[row * BK + ((ch ^ (row & (CH - 1))) << 3)];
      }
#pragma unroll
      for (int i = 0; i < 4; ++i) {
        int row = wc * 64 + i * 16 + (lane & 15);
        bv[i] = *(const bf16x8*)&lds[AE + row * BK + ((ch ^ (row & (CH - 1))) << 3)];
      }
#pragma unroll
      for (int mi = 0; mi < MI; ++mi)
#pragma unroll
        for (int ni = 0; ni < 4; ++ni)
          acc[mi][ni] = __builtin_amdgcn_mfma_f32_16x16x32_bf16(av[mi], bv[ni], acc[mi][ni], 0, 0, 0);
    }
    __syncthreads();
  }

  // ---- epilogue: LDS transpose (row-major fl) -> coalesced wide stores ----
  float* fl = (float*)lds;   // [32 rows][RW cols] f32 = 16.9 KB
  float bb[4];
  if (EPI == 0) {
#pragma unroll
    for (int ni = 0; ni < 4; ++ni)
      bb[ni] = bias[n0 + wc * 64 + ni * 16 + (lane & 15)];
  }
  int rrow = t >> 3;               // 0..31
  int colb = (t & 7) * 16;
#pragma unroll
  for (int mi = 0; mi < MI; ++mi) {
    if (mi) __syncthreads();       // previous readout done before overwrite
    {
      int r0 = (lane >> 4) * 4;
#pragma unroll
      for (int ni = 0; ni < 4; ++ni) {
        int colL = wc * 64 + (lane & 15) + ni * 16;
        f32x4 v = acc[mi][ni];
#pragma unroll
        for (int j = 0; j < 4; ++j) {
          float vj = v[j];
          if (EPI == 0) vj += bb[ni];
          fl[(wr * 16 + r0 + j) * RW + colL] = vj;
        }
      }
    }
    __syncthreads();
    float vv[16];
#pragma unroll
    for (int q = 0; q < 4; ++q)
      *(f32x4*)&vv[q * 4] = *(const f32x4*)&fl[rrow * RW + colb + q * 4];
    int grow = m0 + (rrow >> 4) * (BM / 2) + mi * 16 + (rrow & 15);
    if (EPI == 0) {
      u16x8 o0, o1;
      if (n0 < 1024) {
#pragma unroll
        for (int q = 0; q < 8; ++q) { o0[q] = f2bf(vv[q]); o1[q] = f2bf(vv[8 + q]); }
        unsigned short* dst = (unsigned short*)O0 + (size_t)grow * 1024 + n0 + colb;
        *(u16x8*)dst = o0;
        *(u16x8*)(dst + 8) = o1;
      } else {
#pragma unroll
        for (int q = 0; q < 8; ++q) {
          o0[q] = f2bf(1.f / (1.f + __expf(-vv[q])));
          o1[q] = f2bf(1.f / (1.f + __expf(-vv[8 + q])));
        }
        unsigned short* dst = (unsigned short*)O1 + (size_t)grow * 256 + (n0 - 1024) + colb;
        *(u16x8*)dst = o0;
        *(u16x8*)(dst + 8) = o1;
      }
    } else {
      float* dst = (float*)O0 + (size_t)grow * N + n0 + colb;
#pragma unroll
      for (int q = 0; q < 4; ++q) {
        f32x4 ov = {vv[q * 4], vv[q * 4 + 1], vv[q * 4 + 2], vv[q * 4 + 3]};
        *(f32x4*)(dst + q * 4) = ov;
      }
    }
  }
}

// ---------------- gemm2: double-buffered deep pipeline (R4 exact) ---------------
// R4-verified ~19 us (~900 TF): BM=64/BK=64, NK=16, depth-2 counted-vmcnt
// pipeline, 3 blocks/CU, natural dim3(M/64, 2) grid (R5: XCD remap hurt here).
// Per iter: wait vmcnt(LD) (current step's loads; next step's stay in flight
// ACROSS the barrier), s_barrier, compute, lgkmcnt(0)+s_barrier, stage k+2.
// NEVER __syncthreads in the K-loop (drains vmcnt(0), kills the pipe).
template <int EPI, int BM, int BK>
__global__ __launch_bounds__(256, 3)
void gemm_db(const short* __restrict__ A, const short* __restrict__ Bm,
             const float* __restrict__ bias,
             void* __restrict__ O0, void* __restrict__ O1,
             int M, int N, int K) {
  constexpr int AE = BM * BK;           // shorts in A region of one buffer
  constexpr int BUFS = (BM + 128) * BK; // shorts per buffer
  constexpr int MI = BM / 32;           // m-fragments per wave
  constexpr int CH = BK / 8;            // 16B chunks per row
  constexpr int LA = BM * BK / 2048;    // A gld_lds per thread per step
  constexpr int LB = BK / 16;           // B gld_lds per thread per step
  constexpr int LD = LA + LB;           // loads in flight per step
  constexpr int RW = 132;               // padded row width for epilogue (f32)
  __shared__ __align__(16) short lds[2 * BUFS];

  int t = threadIdx.x;
  int lane = t & 63, wv = t >> 6;
  int wr = wv >> 1, wc = wv & 1;
  int m0 = blockIdx.x * BM, n0 = blockIdx.y * 128;
  const int NK = K / BK;
  f32x4 acc[MI][4] = {};

  float bb[4];
  if (EPI == 0) {
#pragma unroll
    for (int ni = 0; ni < 4; ++ni)
      bb[ni] = bias[n0 + wc * 64 + ni * 16 + (lane & 15)];
  }

  auto STAGE = [&](int step, int bo) {
    int k0 = step * BK;
#pragma unroll
    for (int i = 0; i < LA; ++i) {
      int cc = t + i * 256;
      int row = cc / CH, kc = cc % CH;
      GLD16(A + (size_t)(m0 + row) * K + k0 + ((kc ^ (row & (CH - 1))) << 3),
            &lds[bo + cc * 8]);
    }
#pragma unroll
    for (int i = 0; i < LB; ++i) {
      int cc = t + i * 256;
      int row = cc / CH, kc = cc % CH;
      GLD16(Bm + (size_t)(n0 + row) * K + k0 + ((kc ^ (row & (CH - 1))) << 3),
            &lds[bo + AE + cc * 8]);
    }
  };
  auto COMPUTE = [&](int bo) {
#pragma unroll
    for (int kk = 0; kk < BK / 32; ++kk) {
      int ch = kk * 4 + (lane >> 4);
      bf16x8 av[MI], bv[4];
#pragma unroll
      for (int i = 0; i < MI; ++i) {
        int row = wr * (BM / 2) + i * 16 + (lane & 15);
        av[i] = *(const bf16x8*)&lds[bo + row * BK + ((ch ^ (row & (CH - 1))) << 3)];
      }
#pragma unroll
      for (int i = 0; i < 4; ++i) {
        int row = wc * 64 + i * 16 + (lane & 15);
        bv[i] = *(const bf16x8*)&lds[bo + AE + row * BK + ((ch ^ (row & (CH - 1))) << 3)];
      }
#pragma unroll
      for (int mi = 0; mi < MI; ++mi)
#pragma unroll
        for (int ni = 0; ni < 4; ++ni)
          acc[mi][ni] = __builtin_amdgcn_mfma_f32_16x16x32_bf16(av[mi], bv[ni], acc[mi][ni], 0, 0, 0);
    }
  };

  STAGE(0, 0);
  STAGE(1, BUFS);
#pragma unroll
  for (int k = 0; k < 16; ++k) {      // bounded by max NK; break inside
    if (k >= NK) break;
    int bo = (k & 1) ? BUFS : 0;
    if (k < NK - 1) wait_vm<LD>();
    else wait_vm<0>();
    __builtin_amdgcn_s_barrier();
    COMPUTE(bo);
    asm volatile("s_waitcnt lgkmcnt(0)" ::: "memory");
    __builtin_amdgcn_s_barrier();
    if (k + 2 < NK) STAGE(k + 2, bo);
  }

  // ---- epilogue: LDS transpose (row-major fl) -> coalesced wide stores ----
  float* fl = (float*)lds;   // [32 rows][RW cols] f32 = 16.9 KB
  int rrow = t >> 3;               // 0..31
  int colb = (t & 7) * 16;
#pragma unroll
  for (int mi = 0; mi < MI; ++mi) {
    if (mi) __syncthreads();       // previous readout done before overwrite
    {
      int r0 = (lane >> 4) * 4;
#pragma unroll
      for (int ni = 0; ni < 4; ++ni) {
        int colL = wc * 64 + (lane & 15) + ni * 16;
        f32x4 v = acc[mi][ni];
#pragma unroll
        for (int j = 0; j < 4; ++j) {
          float vj = v[j];
          if (EPI == 0) vj += bb[ni];
          fl[(wr * 16 + r0 + j) * RW + colL] = vj;
        }
      }
    }
    __syncthreads();
    float vv[16];
#pragma unroll
    for (int q = 0; q < 4; ++q)
      *(f32x4*)&vv[q * 4] = *(const f32x4*)&fl[rrow * RW + colb + q * 4];
    int grow = m0 + (rrow >> 4) * (BM / 2) + mi * 16 + (rrow & 15);
    if (EPI == 0) {
      u16x8 o0, o1;
      if (n0 < 1024) {
#pragma unroll
        for (int q = 0; q < 8; ++q) { o0[q] = f2bf(vv[q]); o1[q] = f2bf(vv[8 + q]); }
        unsigned short* dst = (unsigned short*)O0 + (size_t)grow * 1024 + n0 + colb;
        *(u16x8*)dst = o0;
        *(u16x8*)(dst + 8) = o1;
      } else {
#pragma unroll
        for (int q = 0; q < 8; ++q) {
          o0[q] = f2bf(1.f / (1.f + __expf(-vv[q])));
          o1[q] = f2bf(1.f / (1.f + __expf(-vv[8 + q])));
        }
        unsigned short* dst = (unsigned short*)O1 + (size_t)grow * 256 + (n0 - 1024) + colb;
        *(u16x8*)dst = o0;
        *(u16x8*)(dst + 8) = o1;
      }
    } else {
      float* dst = (float*)O0 + (size_t)grow * N + n0 + colb;
#pragma unroll
      for (int q = 0; q < 4; ++q) {
        f32x4 ov = {vv[q * 4], vv[q * 4 + 1], vv[q * 4 + 2], vv[q * 4 + 3]};
        *(f32x4*)(dst + q * 4) = ov;
      }
    }
  }
}

// ---------------- WKV (software-pipelined; 2 ch/thread, interleaved kv) ---------
// R15-verified prefetch pipeline (4-6 outstanding loads/wave).
// R25-verified: chunk 64 (warmup amp 1.5x -> 1.25x) bought ~6.5 us.
// grid 64 x 2(tr) x 8 = 1024 blocks = 4/CU = 16 waves/CU.
__global__ __launch_bounds__(256, 8)
void k_wkv(const unsigned short* __restrict__ kvb, const unsigned short* __restrict__ srb,
           const float* __restrict__ decay, const float* __restrict__ first,
           unsigned short* __restrict__ xssr) {
  const int T = 4096;
  int tid = threadIdx.x;
  int g = tid >> 7;              // 0: k1/v1 half, 1: k3/v3 half
  int l = tid & 127;
  int c0 = l * 2;
  int tr = blockIdx.y;           // 0 natural, 1 transposed scan order
  int s = (g << 1) | tr;         // stream in concat order k1,k2,k3,k4
  int scol = s * 256;
  int chunk = blockIdx.x;        // 0..63, 64 tokens each
  int b = blockIdx.z;
  const float invT = 1.0f / 4096.0f;

  float P0 = 0.f, P1 = 0.f, Q0 = 0.f, Q1 = 0.f;
  float D0 = __expf(-__expf(decay[scol + c0] * invT));
  float D1 = __expf(-__expf(decay[scol + c0 + 1] * invT));
  float eu0 = __expf(first[scol + c0] * invT);
  float eu1 = __expf(first[scol + c0 + 1] * invT);

  int t0 = chunk * 64;
  int tstart = t0 >= 16 ? t0 - 16 : 0;  // 16-step warmup: weight < e^-16 ~ 1e-7
  int tend = t0 + 64;                   // (tend - tstart) is 64 or 80: even
  const size_t bT = (size_t)b * T;
  const int kvoff = (g << 9) + (c0 << 1);  // [half][c][k|v] in shorts

  auto kvload = [&](int tt) {
    int tok = tr ? (((tt & 63) << 6) | (tt >> 6)) : tt;
    return *(const u16x4*)(kvb + (bT + tok) * 1024 + kvoff);
  };
  auto srload = [&](int tt) {
    return *(const u16x2*)(srb + (bT + tt) * 256 + c0);
  };

  // pipeline prologue: 2 iterations in flight
  u16x4 kvA = kvload(tstart);
  u16x4 kvB = kvload(tstart + 1);
  u16x2 svA = srload(tstart);
  u16x2 svB = srload(tstart + 1);

  for (int tt = tstart; tt < tend; tt += 2) {
    // prefetch tt+2 / tt+3 (clamped: last iter re-reads tend-1, harmless)
    int tp2 = tt + 2 < tend ? tt + 2 : tend - 1;
    int tp3 = tt + 3 < tend ? tt + 3 : tend - 1;
    u16x4 kvC = kvload(tp2);
    u16x4 kvD = kvload(tp3);
    u16x2 svC = srload(tp2);
    u16x2 svD = srload(tp3);

#pragma unroll
    for (int u = 0; u < 2; ++u) {
      int ti = tt + u;
      u16x4 kv4 = u ? kvB : kvA;
      u16x2 sv = u ? svB : svA;
      float k0 = bf2f(kv4[0]), v0 = bf2f(kv4[1]);
      float k1 = bf2f(kv4[2]), v1 = bf2f(kv4[3]);
      float e0 = __expf(k0), e1 = __expf(k1);
      if (ti >= t0) {
        float t0e = e0 * eu0, t1e = e1 * eu1;
        float y0 = fmaf(t0e, v0, P0) * __builtin_amdgcn_rcpf(Q0 + t0e);
        float y1 = fmaf(t1e, v1, P1) * __builtin_amdgcn_rcpf(Q1 + t1e);
        u16x2 ow;
        ow[0] = f2bf(y0 * bf2f(sv[0]));
        ow[1] = f2bf(y1 * bf2f(sv[1]));
        *(u16x2*)(xssr + (bT + ti) * 1024 + scol + c0) = ow;
      }
      P0 = fmaf(P0, D0, e0 * v0);
      Q0 = fmaf(Q0, D0, e0);
      P1 = fmaf(P1, D1, e1 * v1);
      Q1 = fmaf(Q1, D1, e1);
    }
    kvA = kvC; kvB = kvD;
    svA = svC; svB = svD;
  }
}

// ---------------- launch ----------------
extern "C" void kernel_launch(void* const* d_in, const int* in_sizes, int n_in,
                              void* d_out, int out_size, void* d_ws, size_t ws_size,
                              hipStream_t stream) {
  const float* x      = (const float*)d_in[0];
  const float* alpha  = (const float*)d_in[1];
  const float* dw1    = (const float*)d_in[2];
  const float* dw3    = (const float*)d_in[3];
  const float* dw5    = (const float*)d_in[4];
  const float* Wk     = (const float*)d_in[5];
  const float* Wv     = (const float*)d_in[6];
  const float* Wr     = (const float*)d_in[7];
  const float* Wf     = (const float*)d_in[8];
  const float* bfv    = (const float*)d_in[9];
  const float* Wb     = (const float*)d_in[10];
  const float* bbv    = (const float*)d_in[11];
  const float* sdecay = (const float*)d_in[12];
  const float* sfirst = (const float*)d_in[13];
  const float* Wo     = (const float*)d_in[14];
  (void)n_in; (void)out_size; (void)ws_size;

  const int Bn = in_sizes[0] / (4096 * 256);  // 8
  const int MT = Bn * 4096;                    // 32768

  char* ws = (char*)d_ws;
  size_t off = 0;
  auto alloc = [&](size_t bytes) {
    void* p = ws + off;
    off += (bytes + 255) & ~(size_t)255;
    return p;
  };
  short* xf            = (short*)alloc((size_t)MT * 256 * 2);
  unsigned short* kv   = (unsigned short*)alloc((size_t)MT * 1024 * 2);
  unsigned short* srb  = (unsigned short*)alloc((size_t)MT * 256 * 2);
  unsigned short* xssr = (unsigned short*)alloc((size_t)MT * 1024 * 2);
  short* wcat          = (short*)alloc((size_t)1280 * 256 * 2);
  float* bias          = (float*)alloc(1280 * 4);
  short* wob           = (short*)alloc((size_t)256 * 1024 * 2);

  // fused prep+shift: 2048 shift + 512 combine + 1024 wo = 3584 blocks, 1 launch.
  k_prep_shift<<<3584, 256, 0, stream>>>(alpha, dw1, dw3, dw5, x,
                                         (unsigned short*)xf,
                                         Wk, Wv, Wr, Wf, Wb, bfv, bbv,
                                         wcat, bias, Wo, wob);
  // gemm1: BM=64 -> 6 blocks/CU (R27-verified, 44 us), XCD A-locality NT=10.
  gemm_bt<0, 64, 64, 10><<<dim3(MT / 64 * 10), 256, 0, stream>>>(
      xf, wcat, bias, kv, srb, MT, 1280, 256);
  // wkv: chunk 64 (R25-verified), 1024 blocks.
  k_wkv<<<dim3(64, 2, Bn), 256, 0, stream>>>(kv, srb, sdecay, sfirst, xssr);
  // gemm2: deep pipe (NK=16), natural grid, 3 blocks/CU (R4 exact).
  gemm_db<1, 64, 64><<<dim3(MT / 64, 2), 256, 0, stream>>>(
      (const short*)xssr, wob, nullptr, d_out, nullptr, MT, 256, 1024);
}